// Round 5
// baseline (2235.464 us; speedup 1.0000x reference)
//
#include <hip/hip_runtime.h>
#include <hip/hip_bf16.h>
#include <stdint.h>

// InvBlock: out = concat(u_new, v_new)
//   v_mid = tanh(u_old @ W1^T + b1); v_new = v_old + 0.1 * (v_mid @ W1)
//   u_mid = tanh(v_new @ W0^T + b0); u_new = u_old - 0.1 * (u_mid @ W0)
// GEMM: 256x256 tile, BK=64, 8 waves, R2's 8-phase schedule (reads+stage
// pre-barrier, lgkm(0) post-barrier, MFMA, barrier), counted vmcnt(6),
// LDS XOR swizzle (T2), setprio (T5), XCD swizzle (T1).
// R5: 32x32x16 MFMA (2382 vs 2075 TF rate, half the MFMA instructions,
// coalesced 64B/128B epilogue stores) — schedule/ledger identical to R2.

typedef __attribute__((ext_vector_type(8))) short short8;    // 8 bf16
typedef __attribute__((ext_vector_type(16))) float f32x16;   // 32x32 acc

#define DEVINL __device__ __forceinline__

DEVINL ushort f2b(float f) {  // fp32 -> bf16 bits, RNE
  union { float f; uint32_t u; } v; v.f = f;
  uint32_t u = v.u;
  return (ushort)((u + 0x7fffu + ((u >> 16) & 1u)) >> 16);
}

DEVINL float fast_tanh(float x) {
  x = fminf(10.0f, fmaxf(-10.0f, x));
  float e = __expf(2.0f * x);
  return (e - 1.0f) * __builtin_amdgcn_rcpf(e + 1.0f);
}

DEVINL void gload16(const ushort* g, ushort* l) {
  __builtin_amdgcn_global_load_lds(
      (const __attribute__((address_space(1))) void*)g,
      (__attribute__((address_space(3))) void*)l, 16, 0, 0);
}

// Quadrant (MH,NH): 2 m-frags x 1 n-frag x 4 ksteps = 8 MFMA 32x32x16.
template<int MH, int NH>
DEVINL void mfma_quad(f32x16 (&acc)[4][2], const short8 (&a)[2][4],
                      const short8 (&b)[4]) {
#pragma unroll
  for (int ks = 0; ks < 4; ++ks)
#pragma unroll
    for (int m2 = 0; m2 < 2; ++m2)
      acc[MH * 2 + m2][NH] = __builtin_amdgcn_mfma_f32_32x32x16_bf16(
          a[m2][ks], b[ks], acc[MH * 2 + m2][NH], 0, 0, 0);
}

// A: M x K bf16 row-major.  Bt: N x K bf16 row-major.
// MODE 0: Tout[m,n] = bf16(tanh(acc + bias[n]))            (ld = N)
// MODE 1: o = xres[m*4096+n] + step*acc -> outres fp32 + vbout bf16 (ld = N)
// MODE 2: same as 1 but no vbout
template<int MODE>
__global__ __launch_bounds__(512, 2)
void gemm256(const ushort* __restrict__ A, const ushort* __restrict__ Bt,
             const float* __restrict__ bias, ushort* __restrict__ Tout,
             const float* __restrict__ xres, float* __restrict__ outres,
             ushort* __restrict__ vbout, float step, int M, int N, int K)
{
  __shared__ __align__(16) ushort ldsU[65536]; // 128 KiB: [buf:2][A 32KB|B 32KB]

  const int tid  = threadIdx.x;
  const int wave = tid >> 6, lane = tid & 63;
  const int wr = wave >> 2, wc = wave & 3;       // 2 x 4 wave grid
  const int lr5 = lane & 31, hi2 = lane >> 5;

  // T1: XCD-aware block swizzle (nwg % 8 == 0 for all our shapes)
  const int GX = gridDim.x;
  const int nwg = GX * gridDim.y;
  const int lin = blockIdx.y * GX + blockIdx.x;
  const int swz = (lin & 7) * (nwg >> 3) + (lin >> 3);
  const int by = swz / GX, bx = swz - by * GX;
  const int m0 = by * 256, n0 = bx * 256;

  // ---- staging source offsets (inverse-swizzled global source, rule #21)
  const int kb_st = ((tid & 7) * 16) ^ (((tid >> 3) & 7) << 4);
  int offA[2][2], offB[2][2];   // [half][j], constant-indexed only
#pragma unroll
  for (int j = 0; j < 2; ++j) {
    const int rp = j * 64 + (tid >> 3);
#pragma unroll
    for (int h = 0; h < 2; ++h) {
      offA[h][j] = (m0 + (rp >> 6) * 128 + h * 64 + (rp & 63)) * K + (kb_st >> 1);
      offB[h][j] = (n0 + (rp >> 5) * 64 + h * 32 + (rp & 31)) * K + (kb_st >> 1);
    }
  }

#define STAGE_A(buf, half, t) do {                                             \
    gload16(A + (size_t)offA[half][0] + (size_t)(t) * 64,                      \
            ldsU + (buf) * 32768 + (half) * 8192 + tid * 8);                   \
    gload16(A + (size_t)offA[half][1] + (size_t)(t) * 64,                      \
            ldsU + (buf) * 32768 + (half) * 8192 + 4096 + tid * 8);            \
  } while (0)
#define STAGE_B(buf, half, t) do {                                             \
    gload16(Bt + (size_t)offB[half][0] + (size_t)(t) * 64,                     \
            ldsU + (buf) * 32768 + 16384 + (half) * 8192 + tid * 8);           \
    gload16(Bt + (size_t)offB[half][1] + (size_t)(t) * 64,                     \
            ldsU + (buf) * 32768 + 16384 + (half) * 8192 + 4096 + tid * 8);    \
  } while (0)

  // ---- fragment-read element offsets (32x32x16: row=lane&31, k=(lane>>5)*8+e)
  const int xm = (lane & 7) << 4;     // swizzle XOR (row&7 == lane&7)
  int kbo[4];                          // per-kstep element offset in row
#pragma unroll
  for (int ks = 0; ks < 4; ++ks)
    kbo[ks] = ((ks * 32 + hi2 * 16) ^ xm) >> 1;
  const int eA = wr * 4096 + lr5 * 64;   // j-region + local row base
  const int eB = wc * 2048 + lr5 * 64;

#define LDSE(idx) (*(const short8*)&ldsU[idx])
#define READ_A8(dst, buf, half) do {                                           \
    _Pragma("unroll")                                                          \
    for (int ks = 0; ks < 4; ++ks) {                                           \
      dst[0][ks] = LDSE((buf)*32768 + (half)*8192 + eA +    0 + kbo[ks]);      \
      dst[1][ks] = LDSE((buf)*32768 + (half)*8192 + eA + 2048 + kbo[ks]);      \
    }                                                                          \
  } while (0)
#define READ_B4(buf, half) do {                                                \
    _Pragma("unroll")                                                          \
    for (int ks = 0; ks < 4; ++ks)                                             \
      b[ks] = LDSE((buf)*32768 + 16384 + (half)*8192 + eB + kbo[ks]);          \
  } while (0)

  f32x16 acc[4][2] = {};
  short8 a0[2][4], a1[2][4], b[4];     // b time-shared between halves

#define PHASE_TAIL(MH, NH, AF)                                                 \
  __builtin_amdgcn_s_barrier();                                                \
  asm volatile("s_waitcnt lgkmcnt(0)" ::: "memory");                           \
  __builtin_amdgcn_sched_barrier(0);                                           \
  __builtin_amdgcn_s_setprio(1);                                               \
  mfma_quad<MH, NH>(acc, AF, b);                                               \
  __builtin_amdgcn_s_setprio(0);                                               \
  __builtin_amdgcn_s_barrier();

  const int NT = K >> 6;        // 64-wide K tiles (even; NT/2 >= 2)
  const int NI = NT >> 1;

  // ---- prologue: buf0 <- tile0 (4 halves), buf1 <- tile1 {A0,B0,A1}
  STAGE_A(0, 0, 0); STAGE_A(0, 1, 0); STAGE_B(0, 0, 0); STAGE_B(0, 1, 0);
  STAGE_A(1, 0, 1); STAGE_B(1, 0, 1); STAGE_A(1, 1, 1);
  asm volatile("s_waitcnt vmcnt(6)" ::: "memory");   // buf0 resident
  __builtin_amdgcn_s_barrier();

  // ---- main loop: iteration i computes tiles 2i (buf0) and 2i+1 (buf1)
#pragma unroll 1
  for (int i = 0; i < NI - 1; ++i) {
    const int t = 2 * i;
    // P1: Q00 buf0
    READ_A8(a0, 0, 0); READ_B4(0, 0);
    STAGE_B(1, 1, t + 1);
    PHASE_TAIL(0, 0, a0)
    // P2: Q10 buf0
    READ_A8(a1, 0, 1);
    STAGE_A(0, 0, t + 2);
    PHASE_TAIL(1, 0, a1)
    // P3: Q01 buf0 (b <- B-half1)
    READ_B4(0, 1);
    STAGE_A(0, 1, t + 2);
    PHASE_TAIL(0, 1, a0)
    // P4: Q11 buf0
    STAGE_B(0, 0, t + 2);
    asm volatile("s_waitcnt vmcnt(6)" ::: "memory");  // buf1(t+1) resident
    PHASE_TAIL(1, 1, a1)
    // P5: Q00 buf1
    READ_A8(a0, 1, 0); READ_B4(1, 0);
    STAGE_B(0, 1, t + 2);
    PHASE_TAIL(0, 0, a0)
    // P6: Q10 buf1
    READ_A8(a1, 1, 1);
    STAGE_A(1, 0, t + 3);
    PHASE_TAIL(1, 0, a1)
    // P7: Q01 buf1
    READ_B4(1, 1);
    STAGE_A(1, 1, t + 3);
    PHASE_TAIL(0, 1, a0)
    // P8: Q11 buf1
    STAGE_B(1, 0, t + 3);
    asm volatile("s_waitcnt vmcnt(6)" ::: "memory");  // buf0(t+2) resident
    PHASE_TAIL(1, 1, a1)
  }

  // ---- peeled final iteration (tiles NT-2, NT-1)
  {
    const int t = NT - 2;
    READ_A8(a0, 0, 0); READ_B4(0, 0);
    STAGE_B(1, 1, t + 1);
    PHASE_TAIL(0, 0, a0)
    READ_A8(a1, 0, 1);
    PHASE_TAIL(1, 0, a1)
    READ_B4(0, 1);
    PHASE_TAIL(0, 1, a0)
    asm volatile("s_waitcnt vmcnt(0)" ::: "memory");  // buf1 fully landed
    PHASE_TAIL(1, 1, a1)
    READ_A8(a0, 1, 0); READ_B4(1, 0);
    PHASE_TAIL(0, 0, a0)
    READ_A8(a1, 1, 1);
    PHASE_TAIL(1, 0, a1)
    READ_B4(1, 1);
    PHASE_TAIL(0, 1, a0)
    PHASE_TAIL(1, 1, a1)
  }

  // ---- epilogue (32x32 C/D): row = m0+wr*128+mi*32+hi2*4+(reg&3)+8*(reg>>2)
  //                            col = n0+wc*64+ni*32+lr5   (32-lane runs!)
  const int mrow0 = m0 + wr * 128 + hi2 * 4;
  const int ncol0 = n0 + wc * 64 + lr5;
  float bv[2];
  if (MODE == 0) { bv[0] = bias[ncol0]; bv[1] = bias[ncol0 + 32]; }
#pragma unroll
  for (int mi = 0; mi < 4; ++mi) {
#pragma unroll
    for (int ni = 0; ni < 2; ++ni) {
      const int col = ncol0 + ni * 32;
#pragma unroll
      for (int reg = 0; reg < 16; ++reg) {
        const int row = mrow0 + mi * 32 + (reg & 3) + 8 * (reg >> 2);
        if (MODE == 0) {
          Tout[(size_t)row * N + col] = f2b(fast_tanh(acc[mi][ni][reg] + bv[ni]));
        } else {
          const size_t oi = (size_t)row * 4096 + col;
          const float v = fmaf(step, acc[mi][ni][reg], xres[oi]);
          outres[oi] = v;
          if (MODE == 1) vbout[(size_t)row * N + col] = f2b(v);
        }
      }
    }
  }
#undef STAGE_A
#undef STAGE_B
#undef LDSE
#undef READ_A8
#undef READ_B4
#undef PHASE_TAIL
}

// u_b[m, 0:2048] = bf16(x[m, 0:2048])   (x has ld 4096)
__global__ void cast_strided_half(const float* __restrict__ x,
                                  ushort* __restrict__ dst)
{
  const int i = blockIdx.x * blockDim.x + threadIdx.x;
  const int row = i >> 9;
  const int c4  = (i & 511) * 4;
  const float4 v = *(const float4*)&x[(size_t)row * 4096 + c4];
  ushort4 o;
  o.x = f2b(v.x); o.y = f2b(v.y); o.z = f2b(v.z); o.w = f2b(v.w);
  *(ushort4*)&dst[(size_t)row * 2048 + c4] = o;
}

// W (4096 x 2048 fp32) -> Wb (4096 x 2048 bf16) and Wt (2048 x 4096 bf16)
__global__ void pack_w(const float* __restrict__ W,
                       ushort* __restrict__ Wb, ushort* __restrict__ Wt)
{
  __shared__ float tile[32][33];
  const int bx = blockIdx.x * 32;
  const int by = blockIdx.y * 32;
  const int tx = threadIdx.x, ty = threadIdx.y;   // 32x8
#pragma unroll
  for (int j = ty; j < 32; j += 8) {
    const float v = W[(size_t)(by + j) * 2048 + bx + tx];
    tile[j][tx] = v;
    Wb[(size_t)(by + j) * 2048 + bx + tx] = f2b(v);
  }
  __syncthreads();
#pragma unroll
  for (int j = ty; j < 32; j += 8) {
    Wt[(size_t)(bx + j) * 4096 + by + tx] = f2b(tile[tx][j]);
  }
}

extern "C" void kernel_launch(void* const* d_in, const int* in_sizes, int n_in,
                              void* d_out, int out_size, void* d_ws, size_t ws_size,
                              hipStream_t stream)
{
  const float* x  = (const float*)d_in[0];   // 16384 x 4096
  const float* W0 = (const float*)d_in[1];   // 4096 x 2048
  const float* b0 = (const float*)d_in[2];
  const float* W1 = (const float*)d_in[3];
  const float* b1 = (const float*)d_in[4];
  float* out = (float*)d_out;                // 16384 x 4096

  const int Mrows = 16384, H2 = 4096, Hh = 2048;

  uint8_t* ws = (uint8_t*)d_ws;
  ushort* T   = (ushort*)ws;                                   // 128 MiB
  ushort* Ab  = (ushort*)(ws + (size_t)134217728);             //  64 MiB
  ushort* W0b = (ushort*)(ws + (size_t)134217728 + 67108864);
  ushort* W0t = W0b + 8388608;
  ushort* W1b = W0t + 8388608;
  ushort* W1t = W1b + 8388608;

  cast_strided_half<<<32768, 256, 0, stream>>>(x, Ab);
  dim3 pw_grid(64, 128), pw_blk(32, 8);
  pack_w<<<pw_grid, pw_blk, 0, stream>>>(W1, W1b, W1t);
  pack_w<<<pw_grid, pw_blk, 0, stream>>>(W0, W0b, W0t);

  dim3 blk(512);
  dim3 g1(H2 / 256, Mrows / 256);   // 16 x 64
  dim3 g2(Hh / 256, Mrows / 256);   //  8 x 64

  // T1 = tanh(u_old @ W1^T + b1)
  gemm256<0><<<g1, blk, 0, stream>>>(Ab, W1b, b1, T,
                                     nullptr, nullptr, nullptr, 0.f,
                                     Mrows, H2, Hh);
  // v_new = v_old + 0.1*(T1 @ W1)  -> out[:,2048:] fp32 + Ab bf16
  gemm256<1><<<g2, blk, 0, stream>>>(T, W1t, nullptr, nullptr,
                                     x + Hh, out + Hh, Ab, 0.1f,
                                     Mrows, Hh, H2);
  // T2 = tanh(v_new @ W0^T + b0)
  gemm256<0><<<g1, blk, 0, stream>>>(Ab, W0b, b0, T,
                                     nullptr, nullptr, nullptr, 0.f,
                                     Mrows, H2, Hh);
  // u_new = u_old - 0.1*(T2 @ W0)  -> out[:,:2048] fp32
  gemm256<2><<<g2, blk, 0, stream>>>(T, W0t, nullptr, nullptr,
                                     x, out, nullptr, -0.1f,
                                     Mrows, Hh, H2);
}

// Round 6
// 1202.256 us; speedup vs baseline: 1.8594x; 1.8594x over previous
//
#include <hip/hip_runtime.h>
#include <hip/hip_bf16.h>
#include <stdint.h>

// InvBlock: out = concat(u_new, v_new)
//   v_mid = tanh(u_old @ W1^T + b1); v_new = v_old + 0.1 * (v_mid @ W1)
//   u_mid = tanh(v_new @ W0^T + b0); u_new = u_old - 0.1 * (u_mid @ W0)
// R6: within-probe A/B. SCHED=0 = R2-exact 8-phase (739 TF baseline).
// SCHED=1 = merged 4-phase: 32 MFMA per barrier-pair, half the sync ops,
// stage placement re-derived so no phase stages a region it reads.
// g1,g2,g4 run SCHED=0; g3 runs SCHED=1 (g1 vs g3: same shape+MODE).

typedef __attribute__((ext_vector_type(8))) short short8;   // 8 bf16 = 4 VGPRs
typedef __attribute__((ext_vector_type(4))) float f32x4;

#define DEVINL __device__ __forceinline__

DEVINL ushort f2b(float f) {  // fp32 -> bf16 bits, RNE
  union { float f; uint32_t u; } v; v.f = f;
  uint32_t u = v.u;
  return (ushort)((u + 0x7fffu + ((u >> 16) & 1u)) >> 16);
}

DEVINL float fast_tanh(float x) {
  x = fminf(10.0f, fmaxf(-10.0f, x));
  float e = __expf(2.0f * x);
  return (e - 1.0f) * __builtin_amdgcn_rcpf(e + 1.0f);
}

DEVINL void gload16(const ushort* g, ushort* l) {
  __builtin_amdgcn_global_load_lds(
      (const __attribute__((address_space(1))) void*)g,
      (__attribute__((address_space(3))) void*)l, 16, 0, 0);
}

template<int MH, int NH>
DEVINL void mfma_quad(f32x4 (&acc)[8][4], const short8 (&a)[4][2],
                      const short8 (&b)[2][2]) {
#pragma unroll
  for (int ks = 0; ks < 2; ++ks)
#pragma unroll
    for (int mi = 0; mi < 4; ++mi)
#pragma unroll
      for (int ni = 0; ni < 2; ++ni)
        acc[MH * 4 + mi][NH * 2 + ni] = __builtin_amdgcn_mfma_f32_16x16x32_bf16(
            a[mi][ks], b[ni][ks], acc[MH * 4 + mi][NH * 2 + ni], 0, 0, 0);
}

// A: M x K bf16 row-major.  Bt: N x K bf16 row-major.
// MODE 0: Tout[m,n] = bf16(tanh(acc + bias[n]))            (ld = N)
// MODE 1: o = xres[m*4096+n] + step*acc -> outres fp32 + vbout bf16 (ld = N)
// MODE 2: same as 1 but no vbout
template<int MODE, int SCHED>
__global__ __launch_bounds__(512, 2)
void gemm256(const ushort* __restrict__ A, const ushort* __restrict__ Bt,
             const float* __restrict__ bias, ushort* __restrict__ Tout,
             const float* __restrict__ xres, float* __restrict__ outres,
             ushort* __restrict__ vbout, float step, int M, int N, int K)
{
  __shared__ __align__(16) ushort ldsU[65536]; // 128 KiB: [buf:2][A 32KB|B 32KB]

  const int tid  = threadIdx.x;
  const int wave = tid >> 6, lane = tid & 63;
  const int wr = wave >> 2, wc = wave & 3;       // 2 x 4 wave grid
  const int lr = lane & 15, hi = lane >> 4;

  // T1: XCD-aware block swizzle (nwg % 8 == 0 for all our shapes)
  const int GX = gridDim.x;
  const int nwg = GX * gridDim.y;
  const int lin = blockIdx.y * GX + blockIdx.x;
  const int swz = (lin & 7) * (nwg >> 3) + (lin >> 3);
  const int by = swz / GX, bx = swz - by * GX;
  const int m0 = by * 256, n0 = bx * 256;

  // ---- staging source offsets (inverse-swizzled global source, rule #21)
  const int kb_st = ((tid & 7) * 16) ^ (((tid >> 3) & 7) << 4);
  int offA[2][2], offB[2][2];   // [half][j], constant-indexed only
#pragma unroll
  for (int j = 0; j < 2; ++j) {
    const int rp = j * 64 + (tid >> 3);
#pragma unroll
    for (int h = 0; h < 2; ++h) {
      offA[h][j] = (m0 + (rp >> 6) * 128 + h * 64 + (rp & 63)) * K + (kb_st >> 1);
      offB[h][j] = (n0 + (rp >> 5) * 64 + h * 32 + (rp & 31)) * K + (kb_st >> 1);
    }
  }

#define STAGE_A(buf, half, t) do {                                             \
    gload16(A + (size_t)offA[half][0] + (size_t)(t) * 64,                      \
            ldsU + (buf) * 32768 + (half) * 8192 + tid * 8);                   \
    gload16(A + (size_t)offA[half][1] + (size_t)(t) * 64,                      \
            ldsU + (buf) * 32768 + (half) * 8192 + 4096 + tid * 8);            \
  } while (0)
#define STAGE_B(buf, half, t) do {                                             \
    gload16(Bt + (size_t)offB[half][0] + (size_t)(t) * 64,                     \
            ldsU + (buf) * 32768 + 16384 + (half) * 8192 + tid * 8);           \
    gload16(Bt + (size_t)offB[half][1] + (size_t)(t) * 64,                     \
            ldsU + (buf) * 32768 + 16384 + (half) * 8192 + 4096 + tid * 8);    \
  } while (0)

  // ---- fragment-read element offsets (ushort units; row&7 == lane&7)
  const int xm = (lane & 7) << 4;
  const int kbr0 = (hi * 16) ^ xm;          // bytes
  const int kbr1 = (64 + hi * 16) ^ xm;
  const int eA0 = (wr * 64 + lr) * 64 + (kbr0 >> 1);
  const int eA1 = (wr * 64 + lr) * 64 + (kbr1 >> 1);
  const int eB0 = (wc * 32 + lr) * 64 + (kbr0 >> 1);
  const int eB1 = (wc * 32 + lr) * 64 + (kbr1 >> 1);

#define LDSE(idx) (*(const short8*)&ldsU[idx])
#define READ_A8(dst, buf, half) do {                                           \
    dst[0][0] = LDSE((buf)*32768 + (half)*8192 +    0 + eA0);                  \
    dst[0][1] = LDSE((buf)*32768 + (half)*8192 +    0 + eA1);                  \
    dst[1][0] = LDSE((buf)*32768 + (half)*8192 + 1024 + eA0);                  \
    dst[1][1] = LDSE((buf)*32768 + (half)*8192 + 1024 + eA1);                  \
    dst[2][0] = LDSE((buf)*32768 + (half)*8192 + 2048 + eA0);                  \
    dst[2][1] = LDSE((buf)*32768 + (half)*8192 + 2048 + eA1);                  \
    dst[3][0] = LDSE((buf)*32768 + (half)*8192 + 3072 + eA0);                  \
    dst[3][1] = LDSE((buf)*32768 + (half)*8192 + 3072 + eA1);                  \
  } while (0)
#define READ_B4(dst, buf, half) do {                                           \
    dst[0][0] = LDSE((buf)*32768 + 16384 + (half)*8192 +    0 + eB0);          \
    dst[0][1] = LDSE((buf)*32768 + 16384 + (half)*8192 +    0 + eB1);          \
    dst[1][0] = LDSE((buf)*32768 + 16384 + (half)*8192 + 1024 + eB0);          \
    dst[1][1] = LDSE((buf)*32768 + 16384 + (half)*8192 + 1024 + eB1);          \
  } while (0)

  f32x4 acc[8][4] = {};
  short8 a0[4][2], a1[4][2], b0[2][2], b1[2][2];

#define VM6 asm volatile("s_waitcnt vmcnt(6)" ::: "memory")
#define VM0 asm volatile("s_waitcnt vmcnt(0)" ::: "memory")
#define PHASE_TAIL(MH, NH, AF, BF)                                             \
  __builtin_amdgcn_s_barrier();                                                \
  asm volatile("s_waitcnt lgkmcnt(0)" ::: "memory");                           \
  __builtin_amdgcn_sched_barrier(0);                                           \
  __builtin_amdgcn_s_setprio(1);                                               \
  mfma_quad<MH, NH>(acc, AF, BF);                                              \
  __builtin_amdgcn_s_setprio(0);                                               \
  __builtin_amdgcn_s_barrier();
#define PHASE_TAIL2(MHa, NHa, AFa, BFa, MHb, NHb, AFb, BFb)                    \
  __builtin_amdgcn_s_barrier();                                                \
  asm volatile("s_waitcnt lgkmcnt(0)" ::: "memory");                           \
  __builtin_amdgcn_sched_barrier(0);                                           \
  __builtin_amdgcn_s_setprio(1);                                               \
  mfma_quad<MHa, NHa>(acc, AFa, BFa);                                          \
  mfma_quad<MHb, NHb>(acc, AFb, BFb);                                          \
  __builtin_amdgcn_s_setprio(0);                                               \
  __builtin_amdgcn_s_barrier();

  const int NT = K >> 6;        // 64-wide K tiles (even; NT/2 >= 2)
  const int NI = NT >> 1;

  // ---- prologue: buf0 <- tile0 (4 halves), buf1 <- tile1 {A0,B0,A1}
  STAGE_A(0, 0, 0); STAGE_A(0, 1, 0); STAGE_B(0, 0, 0); STAGE_B(0, 1, 0);
  STAGE_A(1, 0, 1); STAGE_B(1, 0, 1); STAGE_A(1, 1, 1);
  VM6;                                               // buf0 resident
  __builtin_amdgcn_s_barrier();

  if constexpr (SCHED == 0) {
    // ======== V0: R2-exact 8-phase ========
#pragma unroll 1
    for (int i = 0; i < NI - 1; ++i) {
      const int t = 2 * i;
      READ_A8(a0, 0, 0); READ_B4(b0, 0, 0);
      STAGE_B(1, 1, t + 1);
      PHASE_TAIL(0, 0, a0, b0)
      READ_A8(a1, 0, 1);
      STAGE_A(0, 0, t + 2);
      PHASE_TAIL(1, 0, a1, b0)
      READ_B4(b1, 0, 1);
      STAGE_A(0, 1, t + 2);
      PHASE_TAIL(0, 1, a0, b1)
      STAGE_B(0, 0, t + 2);
      VM6;                                          // buf1(t+1) resident
      PHASE_TAIL(1, 1, a1, b1)
      READ_A8(a0, 1, 0); READ_B4(b0, 1, 0);
      STAGE_B(0, 1, t + 2);
      PHASE_TAIL(0, 0, a0, b0)
      READ_A8(a1, 1, 1);
      STAGE_A(1, 0, t + 3);
      PHASE_TAIL(1, 0, a1, b0)
      READ_B4(b1, 1, 1);
      STAGE_A(1, 1, t + 3);
      PHASE_TAIL(0, 1, a0, b1)
      STAGE_B(1, 0, t + 3);
      VM6;                                          // buf0(t+2) resident
      PHASE_TAIL(1, 1, a1, b1)
    }
    {
      const int t = NT - 2;
      READ_A8(a0, 0, 0); READ_B4(b0, 0, 0);
      STAGE_B(1, 1, t + 1);
      PHASE_TAIL(0, 0, a0, b0)
      READ_A8(a1, 0, 1);
      PHASE_TAIL(1, 0, a1, b0)
      READ_B4(b1, 0, 1);
      PHASE_TAIL(0, 1, a0, b1)
      VM0;                                          // buf1 fully landed
      PHASE_TAIL(1, 1, a1, b1)
      READ_A8(a0, 1, 0); READ_B4(b0, 1, 0);
      PHASE_TAIL(0, 0, a0, b0)
      READ_A8(a1, 1, 1);
      PHASE_TAIL(1, 0, a1, b0)
      READ_B4(b1, 1, 1);
      PHASE_TAIL(0, 1, a0, b1)
      PHASE_TAIL(1, 1, a1, b1)
    }
  } else {
    // ======== V1: merged 4-phase (32 MFMA per barrier-pair) ========
    // Stage placement: no phase stages a region it reads.
    // F1 reads buf0{A-h0,B-h0,A-h1}        stages {B11(t+1)}
    // F2 reads buf0{B-h1}                  stages {A00,A01,B00}(t+2) + vm6
    // F3 reads buf1{A-h0,B-h0,A-h1}        stages {B01(t+2)}
    // F4 reads buf1{B-h1}                  stages {A10,A11,B10}(t+3) + vm6
#pragma unroll 1
    for (int i = 0; i < NI - 1; ++i) {
      const int t = 2 * i;
      READ_A8(a0, 0, 0); READ_B4(b0, 0, 0); READ_A8(a1, 0, 1);
      STAGE_B(1, 1, t + 1);
      PHASE_TAIL2(0, 0, a0, b0, 1, 0, a1, b0)
      READ_B4(b1, 0, 1);
      STAGE_A(0, 0, t + 2); STAGE_A(0, 1, t + 2); STAGE_B(0, 0, t + 2);
      VM6;                                          // buf1(t+1) resident
      PHASE_TAIL2(0, 1, a0, b1, 1, 1, a1, b1)
      READ_A8(a0, 1, 0); READ_B4(b0, 1, 0); READ_A8(a1, 1, 1);
      STAGE_B(0, 1, t + 2);
      PHASE_TAIL2(0, 0, a0, b0, 1, 0, a1, b0)
      READ_B4(b1, 1, 1);
      STAGE_A(1, 0, t + 3); STAGE_A(1, 1, t + 3); STAGE_B(1, 0, t + 3);
      VM6;                                          // buf0(t+2) resident
      PHASE_TAIL2(0, 1, a0, b1, 1, 1, a1, b1)
    }
    {
      const int t = NT - 2;
      READ_A8(a0, 0, 0); READ_B4(b0, 0, 0); READ_A8(a1, 0, 1);
      STAGE_B(1, 1, t + 1);
      PHASE_TAIL2(0, 0, a0, b0, 1, 0, a1, b0)
      READ_B4(b1, 0, 1);
      VM0;                                          // buf1 fully landed
      PHASE_TAIL2(0, 1, a0, b1, 1, 1, a1, b1)
      READ_A8(a0, 1, 0); READ_B4(b0, 1, 0); READ_A8(a1, 1, 1);
      PHASE_TAIL2(0, 0, a0, b0, 1, 0, a1, b0)
      READ_B4(b1, 1, 1);
      PHASE_TAIL2(0, 1, a0, b1, 1, 1, a1, b1)
    }
  }

  // ---- epilogue: C row = m0+wr*128+mi*16+hi*4+r, col = n0+wc*64+ni*16+lr
  const int mrow0 = m0 + wr * 128 + hi * 4;
  const int ncol0 = n0 + wc * 64 + lr;
#pragma unroll
  for (int mi = 0; mi < 8; ++mi) {
#pragma unroll
    for (int ni = 0; ni < 4; ++ni) {
      const int col = ncol0 + ni * 16;
      if (MODE == 0) {
        const float bv = bias[col];
#pragma unroll
        for (int r = 0; r < 4; ++r) {
          const int row = mrow0 + mi * 16 + r;
          Tout[(size_t)row * N + col] = f2b(fast_tanh(acc[mi][ni][r] + bv));
        }
      } else {
#pragma unroll
        for (int r = 0; r < 4; ++r) {
          const int row = mrow0 + mi * 16 + r;
          const size_t oi = (size_t)row * 4096 + col;
          const float v = fmaf(step, acc[mi][ni][r], xres[oi]);
          outres[oi] = v;
          if (MODE == 1) vbout[(size_t)row * N + col] = f2b(v);
        }
      }
    }
  }
#undef STAGE_A
#undef STAGE_B
#undef LDSE
#undef READ_A8
#undef READ_B4
#undef PHASE_TAIL
#undef PHASE_TAIL2
#undef VM6
#undef VM0
}

// u_b[m, 0:2048] = bf16(x[m, 0:2048])   (x has ld 4096)
__global__ void cast_strided_half(const float* __restrict__ x,
                                  ushort* __restrict__ dst)
{
  const int i = blockIdx.x * blockDim.x + threadIdx.x;
  const int row = i >> 9;
  const int c4  = (i & 511) * 4;
  const float4 v = *(const float4*)&x[(size_t)row * 4096 + c4];
  ushort4 o;
  o.x = f2b(v.x); o.y = f2b(v.y); o.z = f2b(v.z); o.w = f2b(v.w);
  *(ushort4*)&dst[(size_t)row * 2048 + c4] = o;
}

// W (4096 x 2048 fp32) -> Wb (4096 x 2048 bf16) and Wt (2048 x 4096 bf16)
__global__ void pack_w(const float* __restrict__ W,
                       ushort* __restrict__ Wb, ushort* __restrict__ Wt)
{
  __shared__ float tile[32][33];
  const int bx = blockIdx.x * 32;
  const int by = blockIdx.y * 32;
  const int tx = threadIdx.x, ty = threadIdx.y;   // 32x8
#pragma unroll
  for (int j = ty; j < 32; j += 8) {
    const float v = W[(size_t)(by + j) * 2048 + bx + tx];
    tile[j][tx] = v;
    Wb[(size_t)(by + j) * 2048 + bx + tx] = f2b(v);
  }
  __syncthreads();
#pragma unroll
  for (int j = ty; j < 32; j += 8) {
    Wt[(size_t)(bx + j) * 4096 + by + tx] = f2b(tile[tx][j]);
  }
}

extern "C" void kernel_launch(void* const* d_in, const int* in_sizes, int n_in,
                              void* d_out, int out_size, void* d_ws, size_t ws_size,
                              hipStream_t stream)
{
  const float* x  = (const float*)d_in[0];   // 16384 x 4096
  const float* W0 = (const float*)d_in[1];   // 4096 x 2048
  const float* b0 = (const float*)d_in[2];
  const float* W1 = (const float*)d_in[3];
  const float* b1 = (const float*)d_in[4];
  float* out = (float*)d_out;                // 16384 x 4096

  const int Mrows = 16384, H2 = 4096, Hh = 2048;

  uint8_t* ws = (uint8_t*)d_ws;
  ushort* T   = (ushort*)ws;                                   // 128 MiB
  ushort* Ab  = (ushort*)(ws + (size_t)134217728);             //  64 MiB
  ushort* W0b = (ushort*)(ws + (size_t)134217728 + 67108864);
  ushort* W0t = W0b + 8388608;
  ushort* W1b = W0t + 8388608;
  ushort* W1t = W1b + 8388608;

  cast_strided_half<<<32768, 256, 0, stream>>>(x, Ab);
  dim3 pw_grid(64, 128), pw_blk(32, 8);
  pack_w<<<pw_grid, pw_blk, 0, stream>>>(W1, W1b, W1t);
  pack_w<<<pw_grid, pw_blk, 0, stream>>>(W0, W0b, W0t);

  dim3 blk(512);
  dim3 g1(H2 / 256, Mrows / 256);   // 16 x 64
  dim3 g2(Hh / 256, Mrows / 256);   //  8 x 64

  // T1 = tanh(u_old @ W1^T + b1)          [V0 arm of A/B]
  gemm256<0, 0><<<g1, blk, 0, stream>>>(Ab, W1b, b1, T,
                                        nullptr, nullptr, nullptr, 0.f,
                                        Mrows, H2, Hh);
  // v_new = v_old + 0.1*(T1 @ W1)  -> out[:,2048:] fp32 + Ab bf16
  gemm256<1, 0><<<g2, blk, 0, stream>>>(T, W1t, nullptr, nullptr,
                                        x + Hh, out + Hh, Ab, 0.1f,
                                        Mrows, Hh, H2);
  // T2 = tanh(v_new @ W0^T + b0)          [V1 arm of A/B]
  gemm256<0, 1><<<g1, blk, 0, stream>>>(Ab, W0b, b0, T,
                                        nullptr, nullptr, nullptr, 0.f,
                                        Mrows, H2, Hh);
  // u_new = u_old - 0.1*(T2 @ W0)  -> out[:,:2048] fp32
  gemm256<2, 0><<<g2, blk, 0, stream>>>(T, W0t, nullptr, nullptr,
                                        x, out, nullptr, -0.1f,
                                        Mrows, Hh, H2);
}